// Round 10
// baseline (544.370 us; speedup 1.0000x reference)
//
#include <hip/hip_runtime.h>
#include <hip/hip_bf16.h>

typedef __attribute__((ext_vector_type(8))) short short8;
typedef __attribute__((ext_vector_type(4))) float f32x4;

#define NB 8
#define NS 1024
#define NH 12
#define ND 64
#define NHID 768
#define N3 2304

#define SBAR() __builtin_amdgcn_sched_barrier(0)

__device__ __forceinline__ unsigned short f2bf(float f) {
  __hip_bfloat16 h = __float2bfloat16(f);
  return *reinterpret_cast<unsigned short*>(&h);
}
__device__ __forceinline__ float bf2f(unsigned short u) {
  __hip_bfloat16 h;
  *reinterpret_cast<unsigned short*>(&h) = u;
  return __bfloat162float(h);
}

// ---- cast hidden f32 -> bf16 ----
__global__ void k_cast(const float* __restrict__ in, unsigned short* __restrict__ out, int n4) {
  int i = blockIdx.x * blockDim.x + threadIdx.x;
  if (i >= n4) return;
  float4 v = ((const float4*)in)[i];
  ushort4 o;
  o.x = f2bf(v.x); o.y = f2bf(v.y); o.z = f2bf(v.z); o.w = f2bf(v.w);
  ((ushort4*)out)[i] = o;
}

// ---- pack mask [B][S] int -> bitmask [B][16] u64 ----
__global__ void k_mask(const int* __restrict__ mask, unsigned long long* __restrict__ bits) {
  int b = blockIdx.x, t = threadIdx.x;
  unsigned long long bal = __ballot(mask[b * NS + t] != 0);
  if ((t & 63) == 0) bits[b * 16 + (t >> 6)] = bal;
}

// ---- transpose-cast W [768][2304] f32 -> Wt [2304][768] bf16 ----
__global__ __launch_bounds__(256) void k_wt(const float* __restrict__ W, unsigned short* __restrict__ Wt) {
  __shared__ float tile[32][33];
  int r0 = blockIdx.x * 32;   // over 768
  int c0 = blockIdx.y * 32;   // over 2304
  int tx = threadIdx.x & 31, ty = threadIdx.x >> 5;
#pragma unroll
  for (int p = 0; p < 4; ++p)
    tile[ty + 8*p][tx] = W[(size_t)(r0 + ty + 8*p) * N3 + c0 + tx];
  __syncthreads();
#pragma unroll
  for (int p = 0; p < 4; ++p)
    Wt[(size_t)(c0 + ty + 8*p) * NHID + r0 + tx] = f2bf(tile[tx][ty + 8*p]);
}

// ---- QKV GEMM: [8192][768]bf16 @ Wt[2304][768]bf16 -> qkv [8192][2304]bf16 ----
__global__ __launch_bounds__(256) void k_qkv(const unsigned short* __restrict__ A,
                                             const unsigned short* __restrict__ Wt,
                                             const float* __restrict__ qb,
                                             const float* __restrict__ vb,
                                             unsigned short* __restrict__ out) {
  const int t = threadIdx.x;
  const int w = t >> 6, l = t & 63, l15 = l & 15, lhi = l >> 4;
  const int rowbase = blockIdx.x * 128 + w * 32;
  const int colbase = blockIdx.y * 64;

  f32x4 acc[2][4] = {};
  const unsigned short* arow0 = A + (size_t)(rowbase + l15) * NHID;
  const unsigned short* arow1 = A + (size_t)(rowbase + 16 + l15) * NHID;
  const unsigned short* wrows[4];
#pragma unroll
  for (int n = 0; n < 4; ++n)
    wrows[n] = Wt + (size_t)(colbase + n * 16 + l15) * NHID;

  for (int k0 = 0; k0 < NHID; k0 += 32) {
    short8 a0 = *(const short8*)(arow0 + k0 + lhi * 8);
    short8 a1 = *(const short8*)(arow1 + k0 + lhi * 8);
#pragma unroll
    for (int n = 0; n < 4; ++n) {
      short8 bfr = *(const short8*)(wrows[n] + k0 + lhi * 8);
      acc[0][n] = __builtin_amdgcn_mfma_f32_16x16x32_bf16(a0, bfr, acc[0][n], 0, 0, 0);
      acc[1][n] = __builtin_amdgcn_mfma_f32_16x16x32_bf16(a1, bfr, acc[1][n], 0, 0, 0);
    }
  }
  const int seg = colbase / NHID;   // uniform per block: 0=q 1=k 2=v
#pragma unroll
  for (int n = 0; n < 4; ++n) {
    int col = colbase + n * 16 + l15;
    int cc = col % NHID;
    float bias = (seg == 0) ? qb[cc] : (seg == 2) ? vb[cc] : 0.0f;
#pragma unroll
    for (int m = 0; m < 2; ++m) {
#pragma unroll
      for (int r = 0; r < 4; ++r) {
        int row = rowbase + m * 16 + lhi * 4 + r;
        float v = acc[m][n][r];
        if (seg == 0) v = (v + bias) * 0.125f;
        else if (seg == 2) v = v + bias;
        out[(size_t)row * N3 + col] = f2bf(v);
      }
    }
  }
}

// ---- transpose V (cols 1536..2303 of qkv) -> Vt [96][64][1024] bf16 ----
__global__ __launch_bounds__(256) void k_vt(const unsigned short* __restrict__ qkvb,
                                            unsigned short* __restrict__ Vt) {
  __shared__ unsigned short tile[32][33];
  int s0 = blockIdx.x * 32;  // over 1024
  int d0 = blockIdx.y * 32;  // over 64
  int bh = blockIdx.z;       // 0..95
  int b = bh / NH;
  int hcol = (bh % NH) * ND;
  int tx = threadIdx.x & 31, ty = threadIdx.x >> 5;
#pragma unroll
  for (int p = 0; p < 4; ++p) {
    int s = s0 + ty + 8*p;
    tile[ty + 8*p][tx] = qkvb[(size_t)(b * NS + s) * N3 + 2 * NHID + hcol + d0 + tx];
  }
  __syncthreads();
#pragma unroll
  for (int p = 0; p < 4; ++p) {
    int d = d0 + ty + 8*p;
    Vt[((size_t)bh * ND + d) * NS + s0 + tx] = tile[tx][ty + 8*p];
  }
}

// ---- fused attention: block (qt,h,b) = 16 q x 1024 keys, 4 waves ----
// rel+rel2 read as FULL 4-KB rows (DRAM-page runs), pre-summed bf16 into
// swizzled relsum[16][1024] LDS once per block. K/V stream in 64-key
// double-buffered wave-private LDS chunks (no barriers in the chunk loop).
// PV consumes 32-key windows every 2 chunks. P packed in 32 VGPRs for probs.
__global__ __launch_bounds__(256, 2) void k_attn(const unsigned short* __restrict__ qkvb,
                                                 const unsigned short* __restrict__ Vt,
                                                 const float* __restrict__ relp,
                                                 const float* __restrict__ rel2,
                                                 const unsigned long long* __restrict__ mbits,
                                                 float* __restrict__ outp) {
  __shared__ __align__(16) unsigned short relsum[16][1024];  // 32 KB, swz ^((row&7)<<4)
  __shared__ __align__(16) char Ks[2][8192];                 // [64 k][128 B] per buf
  __shared__ __align__(16) char Vs[2][8192];                 // [64 d][128 B] per buf
  __shared__ __align__(16) unsigned short stg[4][16][40];    // per-wave P window
  __shared__ float rs_lds[4][16];
  __shared__ float inv_lds[16];

  const int qt = blockIdx.x, h = blockIdx.y, b = blockIdx.z;
  const int t = threadIdx.x, w = t >> 6, l = t & 63, l15 = l & 15, lhi = l >> 4;
  const int bh = b * NH + h;
  const int kx = (l15 & 7) << 4;

  // Q fragments (q already scaled+biased in k_qkv)
  const unsigned short* qrowp = qkvb + (size_t)(b * NS + qt * 16 + l15) * N3 + h * ND;
  short8 qa0 = *(const short8*)(qrowp + lhi * 8);
  short8 qa1 = *(const short8*)(qrowp + 32 + lhi * 8);

  // ---- rel+rel2 full-row staging ----
  const int rrow = t >> 4;                 // 0..15
  const int rcol0 = (t & 15) * 4;          // float col base
  const float* relrow  = relp + ((size_t)bh * NS + qt * 16 + rrow) * NS + rcol0;
  const float* rel2row = rel2 + ((size_t)bh * NS + qt * 16 + rrow) * NS + rcol0;
  const int rwz = (rrow & 7) << 4;
  char* RSrow = (char*)relsum + rrow * 2048;

  short8 kr0, kr1, vr0, vr1;
#define STAGE_LOAD(c) do {                                                     \
    const unsigned short* kg = qkvb + (size_t)(b * NS + (c) * 64 + w * 16 +    \
        (l >> 2)) * N3 + NHID + h * ND + (l & 3) * 16;                         \
    kr0 = *(const short8*)(kg); kr1 = *(const short8*)(kg + 8);                \
    const unsigned short* vg = Vt + (size_t)(bh * ND + l) * NS + (c) * 64 + w * 16; \
    vr0 = *(const short8*)(vg); vr1 = *(const short8*)(vg + 8);                \
  } while (0)

#define STAGE_WRITE(buf) do {                                                  \
    char* KBm = (char*)Ks + (buf) * 8192;                                      \
    int krw = w * 16 + (l >> 2); int kwz2 = (krw & 7) << 4;                    \
    *(short8*)(KBm + krw * 128 + (((l & 3) * 32) ^ kwz2)) = kr0;               \
    *(short8*)(KBm + krw * 128 + (((l & 3) * 32 + 16) ^ kwz2)) = kr1;          \
    char* VBm = (char*)Vs + (buf) * 8192;                                      \
    int vwz2 = (l & 7) << 4;                                                   \
    *(short8*)(VBm + l * 128 + ((w * 32) ^ vwz2)) = vr0;                       \
    *(short8*)(VBm + l * 128 + ((w * 32 + 16) ^ vwz2)) = vr1;                  \
  } while (0)

  float4 ba[8], bb[8];
#pragma unroll
  for (int m = 0; m < 4; ++m) {       // batch 0 -> ba
    ba[m]     = *(const float4*)(relrow  + m * 64);
    ba[4 + m] = *(const float4*)(rel2row + m * 64);
  }
  SBAR();
  STAGE_LOAD(0);                      // K/V chunk 0 rides behind rel batch 0
  SBAR();
#pragma unroll
  for (int j = 0; j < 4; ++j) {       // 1-ahead ping-pong batches
    if (j < 3) {
      float4* nxtb = (j & 1) ? ba : bb;
#pragma unroll
      for (int m = 0; m < 4; ++m) {
        nxtb[m]     = *(const float4*)(relrow  + (j + 1) * 256 + m * 64);
        nxtb[4 + m] = *(const float4*)(rel2row + (j + 1) * 256 + m * 64);
      }
    }
    SBAR();
    float4* curb = (j & 1) ? bb : ba;
#pragma unroll
    for (int m = 0; m < 4; ++m) {
      ushort4 u;
      u.x = f2bf(curb[m].x + curb[4 + m].x);
      u.y = f2bf(curb[m].y + curb[4 + m].y);
      u.z = f2bf(curb[m].z + curb[4 + m].z);
      u.w = f2bf(curb[m].w + curb[4 + m].w);
      int colb = (rcol0 + j * 256 + m * 64) * 2;
      *(ushort4*)(RSrow + (colb ^ rwz)) = u;
    }
    SBAR();
  }
  __syncthreads();                    // relsum visible to all waves

  // ---- barrier-free 16-chunk streaming loop ----
  float rs = 0.f;
  unsigned int pk0[16], pk1[16];
  f32x4 cacc[4] = {};
#pragma unroll
  for (int c = 0; c < 16; ++c) {
    const int buf = c & 1;
    STAGE_WRITE(buf);                 // waits chunk c's loads
    SBAR();
    if (c < 15) STAGE_LOAD(c + 1);    // next chunk in flight across consume
    SBAR();
    // QK^T for this wave's 16 keys of chunk c
    const char* KBc = (const char*)Ks + buf * 8192;
    int krow = w * 16 + l15;
    short8 kf0 = *(const short8*)(KBc + krow * 128 + ((lhi * 16) ^ kx));
    short8 kf1 = *(const short8*)(KBc + krow * 128 + ((64 + lhi * 16) ^ kx));
    f32x4 sc = {};
    sc = __builtin_amdgcn_mfma_f32_16x16x32_bf16(kf0, qa0, sc, 0, 0, 0);
    sc = __builtin_amdgcn_mfma_f32_16x16x32_bf16(kf1, qa1, sc, 0, 0, 0);
    ushort4 rsu = *(const ushort4*)((const char*)relsum + l15 * 2048 +
                                    ((c * 128 + w * 32 + lhi * 8) ^ kx));
    unsigned long long mwc = mbits[b * 16 + c];
    int mb = (int)((mwc >> (w * 16 + lhi * 4)) & 0xFull);
    float p0 = (mb & 1) ? 0.f : __expf(sc[0] + bf2f(rsu.x));
    float p1 = (mb & 2) ? 0.f : __expf(sc[1] + bf2f(rsu.y));
    float p2 = (mb & 4) ? 0.f : __expf(sc[2] + bf2f(rsu.z));
    float p3 = (mb & 8) ? 0.f : __expf(sc[3] + bf2f(rsu.w));
    rs += (p0 + p1) + (p2 + p3);
    ushort4 pw;
    pw.x = f2bf(p0); pw.y = f2bf(p1); pw.z = f2bf(p2); pw.w = f2bf(p3);
    pk0[c] = (unsigned int)pw.x | ((unsigned int)pw.y << 16);
    pk1[c] = (unsigned int)pw.z | ((unsigned int)pw.w << 16);
    *(ushort4*)(&stg[w][l15][(c & 1) * 16 + lhi * 4]) = pw;
    if (c & 1) {                      // 32-key window complete -> PV
      short8 pa = *(const short8*)(&stg[w][l15][lhi * 8]);
      const char* VBc = (const char*)Vs + ((lhi >> 1) ? 8192 : 0);  // buf0=prev,buf1=cur
      int vcol = w * 32 + (lhi & 1) * 16;
#pragma unroll
      for (int n = 0; n < 4; ++n) {
        int dr = n * 16 + l15;
        short8 vf = *(const short8*)(VBc + dr * 128 + (vcol ^ kx));
        cacc[n] = __builtin_amdgcn_mfma_f32_16x16x32_bf16(pa, vf, cacc[n], 0, 0, 0);
      }
    }
  }

  // row sums -> inv (one barrier pair)
  rs += __shfl_xor(rs, 16);
  rs += __shfl_xor(rs, 32);
  if (lhi == 0) rs_lds[w][l15] = rs;
  __syncthreads();
  if (t < 16)
    inv_lds[t] = 1.0f / (rs_lds[0][t] + rs_lds[1][t] + rs_lds[2][t] + rs_lds[3][t]);
  __syncthreads();

  // probs out from pk regs: row = qt*16+l15, col = c*64 + w*16 + lhi*4
  {
    float* probs = outp + (size_t)NB * NS * NHID;
    float inv = inv_lds[l15];
    size_t prow = ((size_t)bh * NS + qt * 16 + l15) * NS + w * 16 + lhi * 4;
#pragma unroll
    for (int c = 0; c < 16; ++c) {
      unsigned int u0 = pk0[c], u1 = pk1[c];
      float4 o;
      o.x = __uint_as_float(u0 << 16) * inv;
      o.y = __uint_as_float(u0 & 0xFFFF0000u) * inv;
      o.z = __uint_as_float(u1 << 16) * inv;
      o.w = __uint_as_float(u1 & 0xFFFF0000u) * inv;
      *(float4*)(&probs[prow + c * 64]) = o;
    }
  }

  // ctx: cross-wave reduce via reuse of Ks (16 KB) -- safe: past the barrier
  float* cpart = (float*)Ks;
#pragma unroll
  for (int n = 0; n < 4; ++n)
#pragma unroll
    for (int r = 0; r < 4; ++r)
      cpart[w * 1024 + (lhi * 4 + r) * 64 + n * 16 + l15] = cacc[n][r];
  __syncthreads();
#pragma unroll
  for (int i = 0; i < 4; ++i) {
    int idx = t + 256 * i;
    int q = idx >> 6, d = idx & 63;
    float s = cpart[idx] + cpart[1024 + idx] + cpart[2048 + idx] + cpart[3072 + idx];
    outp[(size_t)(b * NS + qt * 16 + q) * NHID + h * ND + d] = s * inv_lds[q];
  }
#undef STAGE_LOAD
#undef STAGE_WRITE
}

extern "C" void kernel_launch(void* const* d_in, const int* in_sizes, int n_in,
                              void* d_out, int out_size, void* d_ws, size_t ws_size,
                              hipStream_t stream) {
  const float* hidden = (const float*)d_in[0];
  const int* mask = (const int*)d_in[1];
  const float* relp = (const float*)d_in[2];
  const float* rel2 = (const float*)d_in[3];
  const float* Wq = (const float*)d_in[4];
  const float* qb = (const float*)d_in[5];
  const float* vb = (const float*)d_in[6];
  float* out = (float*)d_out;

  const size_t OFF_AHS = 0;                       // 8192*768*2
  const size_t OFF_WT  = 12582912;                // 2304*768*2
  const size_t OFF_QKV = 16121856;                // 8192*2304*2
  const size_t OFF_VT  = 53870592;                // 96*64*1024*2
  const size_t OFF_MB  = 66453504;                // 8*16*8 = 1024
  if (ws_size < 66454528) return;

  char* ws = (char*)d_ws;
  unsigned short* Ahs  = (unsigned short*)(ws + OFF_AHS);
  unsigned short* Wt   = (unsigned short*)(ws + OFF_WT);
  unsigned short* qkvb = (unsigned short*)(ws + OFF_QKV);
  unsigned short* Vt   = (unsigned short*)(ws + OFF_VT);
  unsigned long long* mb = (unsigned long long*)(ws + OFF_MB);

  k_cast<<<dim3(6144), dim3(256), 0, stream>>>(hidden, Ahs, (NB * NS * NHID) / 4);
  k_mask<<<dim3(8), dim3(1024), 0, stream>>>(mask, mb);
  k_wt<<<dim3(24, 72), dim3(256), 0, stream>>>(Wq, Wt);
  k_qkv<<<dim3(64, 36), dim3(256), 0, stream>>>(Ahs, Wt, qb, vb, qkvb);
  k_vt<<<dim3(32, 2, 96), dim3(256), 0, stream>>>(qkvb, Vt);
  k_attn<<<dim3(64, 12, 8), dim3(256), 0, stream>>>(qkvb, Vt, relp, rel2, mb, out);
}

// Round 11
// 373.653 us; speedup vs baseline: 1.4569x; 1.4569x over previous
//
#include <hip/hip_runtime.h>
#include <hip/hip_bf16.h>

typedef __attribute__((ext_vector_type(8))) short short8;
typedef __attribute__((ext_vector_type(4))) float f32x4;

#define NB 8
#define NS 1024
#define NH 12
#define ND 64
#define NHID 768
#define N3 2304

#define SBAR() __builtin_amdgcn_sched_barrier(0)

__device__ __forceinline__ unsigned short f2bf(float f) {
  __hip_bfloat16 h = __float2bfloat16(f);
  return *reinterpret_cast<unsigned short*>(&h);
}
__device__ __forceinline__ float bf2f(unsigned short u) {
  __hip_bfloat16 h;
  *reinterpret_cast<unsigned short*>(&h) = u;
  return __bfloat162float(h);
}

__device__ __forceinline__ void gload_lds16(const unsigned short* g, unsigned short* l) {
  __builtin_amdgcn_global_load_lds(
      (const __attribute__((address_space(1))) unsigned int*)g,
      (__attribute__((address_space(3))) unsigned int*)l, 16, 0, 0);
}

// ---- cast hidden f32 -> bf16 ----
__global__ void k_cast(const float* __restrict__ in, unsigned short* __restrict__ out, int n4) {
  int i = blockIdx.x * blockDim.x + threadIdx.x;
  if (i >= n4) return;
  float4 v = ((const float4*)in)[i];
  ushort4 o;
  o.x = f2bf(v.x); o.y = f2bf(v.y); o.z = f2bf(v.z); o.w = f2bf(v.w);
  ((ushort4*)out)[i] = o;
}

// ---- pack mask [B][S] int -> bitmask [B][16] u64 ----
__global__ void k_mask(const int* __restrict__ mask, unsigned long long* __restrict__ bits) {
  int b = blockIdx.x, t = threadIdx.x;
  unsigned long long bal = __ballot(mask[b * NS + t] != 0);
  if ((t & 63) == 0) bits[b * 16 + (t >> 6)] = bal;
}

// ---- transpose-cast W [768][2304] f32 -> Wt [2304][768] bf16 ----
__global__ __launch_bounds__(256) void k_wt(const float* __restrict__ W, unsigned short* __restrict__ Wt) {
  __shared__ float tile[32][33];
  int r0 = blockIdx.x * 32;   // over 768
  int c0 = blockIdx.y * 32;   // over 2304
  int tx = threadIdx.x & 31, ty = threadIdx.x >> 5;
#pragma unroll
  for (int p = 0; p < 4; ++p)
    tile[ty + 8*p][tx] = W[(size_t)(r0 + ty + 8*p) * N3 + c0 + tx];
  __syncthreads();
#pragma unroll
  for (int p = 0; p < 4; ++p)
    Wt[(size_t)(c0 + ty + 8*p) * NHID + r0 + tx] = f2bf(tile[tx][ty + 8*p]);
}

// ---- QKV GEMM (m97-style): C[8192][2304] = A[8192][768] . Wt[2304][768]^T ----
// 128x128 tile, 4 waves (2x2), BK=32, global_load_lds width-16 staging,
// 2-barrier K-loop, 16 MFMA + 8 ds_read_b128 per K-step per wave.
__global__ __launch_bounds__(256) void k_qkv(const unsigned short* __restrict__ A,
                                             const unsigned short* __restrict__ Wt,
                                             const float* __restrict__ qb,
                                             const float* __restrict__ vb,
                                             unsigned short* __restrict__ out) {
  __shared__ __align__(16) unsigned short As[128 * 32];
  __shared__ __align__(16) unsigned short Bs[128 * 32];
  const int t = threadIdx.x;
  const int w = t >> 6, l = t & 63, l15 = l & 15, lhi = l >> 4;
  const int wr = w >> 1, wc = w & 1;
  const int rowbase = blockIdx.x * 128;
  const int colbase = blockIdx.y * 128;
  const int srow = l >> 2;           // 0..15 within a 16-row staging instr
  const int scol = (l & 3) * 8;      // shorts

  f32x4 acc[4][4] = {};

  for (int k0 = 0; k0 < NHID; k0 += 32) {
    __syncthreads();   // previous consume done before overwrite
#pragma unroll
    for (int i = 0; i < 2; ++i) {
      int rr = w * 32 + i * 16;
      gload_lds16(A  + (size_t)(rowbase + rr + srow) * NHID + k0 + scol, As + rr * 32);
      gload_lds16(Wt + (size_t)(colbase + rr + srow) * NHID + k0 + scol, Bs + rr * 32);
    }
    __syncthreads();   // compiler drains vmcnt before barrier -> staged data visible
    short8 a[4], bfr[4];
#pragma unroll
    for (int mi = 0; mi < 4; ++mi)
      a[mi] = *(const short8*)(As + (wr * 64 + mi * 16 + l15) * 32 + lhi * 8);
#pragma unroll
    for (int ni = 0; ni < 4; ++ni)
      bfr[ni] = *(const short8*)(Bs + (wc * 64 + ni * 16 + l15) * 32 + lhi * 8);
#pragma unroll
    for (int mi = 0; mi < 4; ++mi)
#pragma unroll
      for (int ni = 0; ni < 4; ++ni)
        acc[mi][ni] = __builtin_amdgcn_mfma_f32_16x16x32_bf16(a[mi], bfr[ni], acc[mi][ni], 0, 0, 0);
  }

  const int seg = colbase / NHID;    // 768 % 128 == 0 -> block-uniform
#pragma unroll
  for (int ni = 0; ni < 4; ++ni) {
    int col = colbase + wc * 64 + ni * 16 + l15;
    int cc = col % NHID;
    float bias = (seg == 0) ? qb[cc] : (seg == 2) ? vb[cc] : 0.0f;
#pragma unroll
    for (int mi = 0; mi < 4; ++mi)
#pragma unroll
      for (int r = 0; r < 4; ++r) {
        int row = rowbase + wr * 64 + mi * 16 + lhi * 4 + r;
        float v = acc[mi][ni][r];
        if (seg == 0) v = (v + bias) * 0.125f;
        else if (seg == 2) v = v + bias;
        out[(size_t)row * N3 + col] = f2bf(v);
      }
  }
}

// ---- transpose V (cols 1536..2303 of qkv) -> Vt [96][64][1024] bf16 ----
__global__ __launch_bounds__(256) void k_vt(const unsigned short* __restrict__ qkvb,
                                            unsigned short* __restrict__ Vt) {
  __shared__ unsigned short tile[32][33];
  int s0 = blockIdx.x * 32;  // over 1024
  int d0 = blockIdx.y * 32;  // over 64
  int bh = blockIdx.z;       // 0..95
  int b = bh / NH;
  int hcol = (bh % NH) * ND;
  int tx = threadIdx.x & 31, ty = threadIdx.x >> 5;
#pragma unroll
  for (int p = 0; p < 4; ++p) {
    int s = s0 + ty + 8*p;
    tile[ty + 8*p][tx] = qkvb[(size_t)(b * NS + s) * N3 + 2 * NHID + hcol + d0 + tx];
  }
  __syncthreads();
#pragma unroll
  for (int p = 0; p < 4; ++p) {
    int d = d0 + ty + 8*p;
    Vt[((size_t)bh * ND + d) * NS + s0 + tx] = tile[tx][ty + 8*p];
  }
}

// ---- fused attention (R8 structure + bank-conflict rotation) ----
// Block (qt,h,b): 16 q x 1024 keys, 4 waves, 8 chunks of 128 keys.
// Per chunk: reg-stage K(16K)+V(16K)+relsum(4K) into XOR-swizzled LDS
// (double-buffered); K/V chunk placement rotated per row-octave so the 4
// previously-aliasing lanes hit 4 distinct bank groups; reads un-rotate.
__global__ __launch_bounds__(256, 2) void k_attn(const unsigned short* __restrict__ qkvb,
                                                 const unsigned short* __restrict__ Vt,
                                                 const float* __restrict__ relp,
                                                 const float* __restrict__ rel2,
                                                 const unsigned long long* __restrict__ mbits,
                                                 float* __restrict__ outp) {
  __shared__ __align__(16) char Ks[2][16384];           // [128 key][64 d] bf16, swz+rot
  __shared__ __align__(16) char Vs[2][16384];           // [64 d][128 key] bf16, swz+rot
  __shared__ __align__(16) char Rs[2][4096];            // [16 q][128 key] bf16 relsum, swz
  __shared__ __align__(16) unsigned short stg[4][16][40]; // per-wave P window
  __shared__ float rs_lds[4][16];
  __shared__ float inv_lds[16];

  const int qt = blockIdx.x, h = blockIdx.y, b = blockIdx.z;
  const int t = threadIdx.x, w = t >> 6, l = t & 63, l15 = l & 15, lhi = l >> 4;
  const int bh = b * NH + h;

  // staging thread->data mapping (block-wide, per chunk)
  const int skk = t >> 1;            // K key-row 0..127
  const int skc = (t & 1) * 64;      // K byte-col base
  const int svd = t >> 2;            // V d-row 0..63
  const int svc = (t & 3) * 64;      // V byte-col base
  const int srr = t >> 4;            // rel q-row 0..15
  const int src = (t & 15) * 8;      // rel f32-col base
  const int kwz = (skk & 7) << 4, vwz = (svd & 7) << 4, rwz = (srr & 7) << 4;
  const int rotw = (skk >> 3) & 3;                           // K write rotation
  const int rotv = ((svd >> 3) & 1) + 2 * ((svc >> 7) & 1);  // V write rotation

  // Q fragments (q already scaled+biased in k_qkv)
  const unsigned short* qrowp = qkvb + (size_t)(b * NS + qt * 16 + l15) * N3 + h * ND;
  short8 qa0 = *(const short8*)(qrowp + lhi * 8);
  short8 qa1 = *(const short8*)(qrowp + 32 + lhi * 8);

  unsigned long long mw[8];
#pragma unroll
  for (int c = 0; c < 8; ++c) mw[c] = mbits[b * 16 + c * 2 + (w >> 1)];

  const unsigned short* kgbase = qkvb + (size_t)(b * NS + skk) * N3 + NHID + h * ND + (skc >> 1);
  const unsigned short* vgbase = Vt + (size_t)(bh * ND + svd) * NS + (svc >> 1);
  const float* rgbase  = relp + ((size_t)(bh * NS + qt * 16 + srr)) * NS + src;
  const float* r2gbase = rel2 + ((size_t)(bh * NS + qt * 16 + srr)) * NS + src;

  short8 kr0, kr1, kr2, kr3, vr0, vr1, vr2, vr3;
  float4 ra0, ra1, rb0, rb1;

#define STAGE_LOAD(c) do {                                              \
    const unsigned short* kg = kgbase + (size_t)(c) * 128 * N3;         \
    kr0 = *(const short8*)(kg);      kr1 = *(const short8*)(kg + 8);    \
    kr2 = *(const short8*)(kg + 16); kr3 = *(const short8*)(kg + 24);   \
    const unsigned short* vg = vgbase + (c) * 128;                      \
    vr0 = *(const short8*)(vg);      vr1 = *(const short8*)(vg + 8);    \
    vr2 = *(const short8*)(vg + 16); vr3 = *(const short8*)(vg + 24);   \
    const float* rg = rgbase + (c) * 128;                               \
    ra0 = *(const float4*)(rg);  ra1 = *(const float4*)(rg + 4);        \
    const float* r2g = r2gbase + (c) * 128;                             \
    rb0 = *(const float4*)(r2g); rb1 = *(const float4*)(r2g + 4);       \
  } while (0)

#define STAGE_WRITE(buf) do {                                                     \
    char* KB = Ks[buf];                                                           \
    *(short8*)(KB + skk * 128 + ((skc + 16 * ((0 + rotw) & 3)) ^ kwz)) = kr0;     \
    *(short8*)(KB + skk * 128 + ((skc + 16 * ((1 + rotw) & 3)) ^ kwz)) = kr1;     \
    *(short8*)(KB + skk * 128 + ((skc + 16 * ((2 + rotw) & 3)) ^ kwz)) = kr2;     \
    *(short8*)(KB + skk * 128 + ((skc + 16 * ((3 + rotw) & 3)) ^ kwz)) = kr3;     \
    char* VB = Vs[buf];                                                           \
    *(short8*)(VB + svd * 256 + ((svc + 16 * ((0 + rotv) & 3)) ^ vwz)) = vr0;     \
    *(short8*)(VB + svd * 256 + ((svc + 16 * ((1 + rotv) & 3)) ^ vwz)) = vr1;     \
    *(short8*)(VB + svd * 256 + ((svc + 16 * ((2 + rotv) & 3)) ^ vwz)) = vr2;     \
    *(short8*)(VB + svd * 256 + ((svc + 16 * ((3 + rotv) & 3)) ^ vwz)) = vr3;     \
    char* RB = Rs[buf];                                                           \
    ushort4 u0, u1;                                                               \
    u0.x = f2bf(ra0.x + rb0.x); u0.y = f2bf(ra0.y + rb0.y);                       \
    u0.z = f2bf(ra0.z + rb0.z); u0.w = f2bf(ra0.w + rb0.w);                       \
    u1.x = f2bf(ra1.x + rb1.x); u1.y = f2bf(ra1.y + rb1.y);                       \
    u1.z = f2bf(ra1.z + rb1.z); u1.w = f2bf(ra1.w + rb1.w);                       \
    *(ushort4*)(RB + srr * 256 + ((src * 2 + 0) ^ rwz)) = u0;                     \
    *(ushort4*)(RB + srr * 256 + ((src * 2 + 8) ^ rwz)) = u1;                     \
  } while (0)

  unsigned int pkA[8][2], pkB[8][2];
  f32x4 cacc[4] = {};
  float rs = 0.f;

  STAGE_LOAD(0);
#pragma unroll
  for (int c = 0; c < 8; ++c) {
    const int buf = c & 1;
    STAGE_WRITE(buf);              // waits chunk c's loads (issued last iter)
    SBAR();
    if (c < 7) STAGE_LOAD(c + 1);  // in flight across the whole consume
    SBAR();
    __syncthreads();               // chunk c visible to all waves

    // ---- consume chunk c ----
    const char* KB = Ks[buf]; const char* VB = Vs[buf]; const char* RB = Rs[buf];
#pragma unroll
    for (int s = 0; s < 2; ++s) {
      int kkr = w * 32 + s * 16 + l15;
      int kx = (kkr & 7) << 4;
      int rotr = (kkr >> 3) & 3;
      short8 kf0 = *(const short8*)(KB + kkr * 128 + ((16 * ((lhi + rotr) & 3)) ^ kx));
      short8 kf1 = *(const short8*)(KB + kkr * 128 + ((64 + 16 * ((lhi + rotr) & 3)) ^ kx));
      f32x4 sc = {};
      sc = __builtin_amdgcn_mfma_f32_16x16x32_bf16(kf0, qa0, sc, 0, 0, 0);
      sc = __builtin_amdgcn_mfma_f32_16x16x32_bf16(kf1, qa1, sc, 0, 0, 0);
      ushort4 rsu = *(const ushort4*)(RB + l15 * 256 + ((w * 64 + s * 32 + lhi * 8) ^ ((l15 & 7) << 4)));
      int mb = (int)((mw[c] >> ((w & 1) * 32 + s * 16 + lhi * 4)) & 0xFull);
      float p0 = (mb & 1) ? 0.f : __expf(sc[0] + bf2f(rsu.x));
      float p1 = (mb & 2) ? 0.f : __expf(sc[1] + bf2f(rsu.y));
      float p2 = (mb & 4) ? 0.f : __expf(sc[2] + bf2f(rsu.z));
      float p3 = (mb & 8) ? 0.f : __expf(sc[3] + bf2f(rsu.w));
      rs += (p0 + p1) + (p2 + p3);
      ushort4 pw;
      pw.x = f2bf(p0); pw.y = f2bf(p1); pw.z = f2bf(p2); pw.w = f2bf(p3);
      pkA[c][s] = (unsigned int)pw.x | ((unsigned int)pw.y << 16);
      pkB[c][s] = (unsigned int)pw.z | ((unsigned int)pw.w << 16);
      *(ushort4*)(&stg[w][l15][s * 16 + lhi * 4]) = pw;
    }
    SBAR();                        // stage writes before pa read (wave in-order)
    short8 pa = *(const short8*)(&stg[w][l15][lhi * 8]);
#pragma unroll
    for (int n = 0; n < 4; ++n) {
      int dr = n * 16 + l15;
      int rotvr = ((dr >> 3) & 1) + 2 * ((w >> 1) & 1);
      short8 vf = *(const short8*)(VB + dr * 256 + ((w * 64 + 16 * ((lhi + rotvr) & 3)) ^ ((dr & 7) << 4)));
      cacc[n] = __builtin_amdgcn_mfma_f32_16x16x32_bf16(pa, vf, cacc[n], 0, 0, 0);
    }
  }

  // row sums -> inv
  rs += __shfl_xor(rs, 16);
  rs += __shfl_xor(rs, 32);
  if (lhi == 0) rs_lds[w][l15] = rs;
  __syncthreads();
  if (t < 16)
    inv_lds[t] = 1.0f / (rs_lds[0][t] + rs_lds[1][t] + rs_lds[2][t] + rs_lds[3][t]);
  __syncthreads();

  // probs out from pk regs: row = qt*16 + l15, col = c*128 + w*32 + s*16 + lhi*4
  {
    float* probs = outp + (size_t)NB * NS * NHID;
    float inv = inv_lds[l15];
    size_t prow = ((size_t)bh * NS + qt * 16 + l15) * NS;
#pragma unroll
    for (int c = 0; c < 8; ++c)
#pragma unroll
      for (int s = 0; s < 2; ++s) {
        int col = c * 128 + w * 32 + s * 16 + lhi * 4;
        unsigned int u0 = pkA[c][s], u1 = pkB[c][s];
        float4 o;
        o.x = __uint_as_float(u0 << 16) * inv;
        o.y = __uint_as_float(u0 & 0xFFFF0000u) * inv;
        o.z = __uint_as_float(u1 << 16) * inv;
        o.w = __uint_as_float(u1 & 0xFFFF0000u) * inv;
        *(float4*)(&probs[prow + col]) = o;
      }
  }

  // ctx: cross-wave reduce via reuse of Ks (16 KB) -- safe: past the barrier
  float* cpart = (float*)Ks;
#pragma unroll
  for (int n = 0; n < 4; ++n)
#pragma unroll
    for (int r = 0; r < 4; ++r)
      cpart[w * 1024 + (lhi * 4 + r) * 64 + n * 16 + l15] = cacc[n][r];
  __syncthreads();
#pragma unroll
  for (int i = 0; i < 4; ++i) {
    int idx = t + 256 * i;
    int q = idx >> 6, d = idx & 63;
    float s = cpart[idx] + cpart[1024 + idx] + cpart[2048 + idx] + cpart[3072 + idx];
    outp[(size_t)(b * NS + qt * 16 + q) * NHID + h * ND + d] = s * inv_lds[q];
  }
#undef STAGE_LOAD
#undef STAGE_WRITE
}

extern "C" void kernel_launch(void* const* d_in, const int* in_sizes, int n_in,
                              void* d_out, int out_size, void* d_ws, size_t ws_size,
                              hipStream_t stream) {
  const float* hidden = (const float*)d_in[0];
  const int* mask = (const int*)d_in[1];
  const float* relp = (const float*)d_in[2];
  const float* rel2 = (const float*)d_in[3];
  const float* Wq = (const float*)d_in[4];
  const float* qb = (const float*)d_in[5];
  const float* vb = (const float*)d_in[6];
  float* out = (float*)d_out;

  const size_t OFF_AHS = 0;                       // 8192*768*2
  const size_t OFF_WT  = 12582912;                // 2304*768*2
  const size_t OFF_QKV = 16121856;                // 8192*2304*2
  const size_t OFF_VT  = 53870592;                // 96*64*1024*2
  const size_t OFF_MB  = 66453504;                // 8*16*8 = 1024
  if (ws_size < 66454528) return;

  char* ws = (char*)d_ws;
  unsigned short* Ahs  = (unsigned short*)(ws + OFF_AHS);
  unsigned short* Wt   = (unsigned short*)(ws + OFF_WT);
  unsigned short* qkvb = (unsigned short*)(ws + OFF_QKV);
  unsigned short* Vt   = (unsigned short*)(ws + OFF_VT);
  unsigned long long* mb = (unsigned long long*)(ws + OFF_MB);

  k_cast<<<dim3(6144), dim3(256), 0, stream>>>(hidden, Ahs, (NB * NS * NHID) / 4);
  k_mask<<<dim3(8), dim3(1024), 0, stream>>>(mask, mb);
  k_wt<<<dim3(24, 72), dim3(256), 0, stream>>>(Wq, Wt);
  k_qkv<<<dim3(64, 18), dim3(256), 0, stream>>>(Ahs, Wt, qb, vb, qkvb);
  k_vt<<<dim3(32, 2, 96), dim3(256), 0, stream>>>(qkvb, Vt);
  k_attn<<<dim3(64, 12, 8), dim3(256), 0, stream>>>(qkvb, Vt, relp, rel2, mb, out);
}

// Round 12
// 362.533 us; speedup vs baseline: 1.5016x; 1.0307x over previous
//
#include <hip/hip_runtime.h>
#include <hip/hip_bf16.h>

typedef __attribute__((ext_vector_type(8))) short short8;
typedef __attribute__((ext_vector_type(4))) float f32x4;

#define NB 8
#define NS 1024
#define NH 12
#define ND 64
#define NHID 768
#define N3 2304

#define SBAR() __builtin_amdgcn_sched_barrier(0)

__device__ __forceinline__ unsigned short f2bf(float f) {
  __hip_bfloat16 h = __float2bfloat16(f);
  return *reinterpret_cast<unsigned short*>(&h);
}
__device__ __forceinline__ float bf2f(unsigned short u) {
  __hip_bfloat16 h;
  *reinterpret_cast<unsigned short*>(&h) = u;
  return __bfloat162float(h);
}

__device__ __forceinline__ void gload_lds16(const unsigned short* g, unsigned short* l) {
  __builtin_amdgcn_global_load_lds(
      (const __attribute__((address_space(1))) unsigned int*)g,
      (__attribute__((address_space(3))) unsigned int*)l, 16, 0, 0);
}

// ---- cast hidden f32 -> bf16 ----
__global__ void k_cast(const float* __restrict__ in, unsigned short* __restrict__ out, int n4) {
  int i = blockIdx.x * blockDim.x + threadIdx.x;
  if (i >= n4) return;
  float4 v = ((const float4*)in)[i];
  ushort4 o;
  o.x = f2bf(v.x); o.y = f2bf(v.y); o.z = f2bf(v.z); o.w = f2bf(v.w);
  ((ushort4*)out)[i] = o;
}

// ---- pack mask [B][S] int -> bitmask [B][16] u64 ----
__global__ void k_mask(const int* __restrict__ mask, unsigned long long* __restrict__ bits) {
  int b = blockIdx.x, t = threadIdx.x;
  unsigned long long bal = __ballot(mask[b * NS + t] != 0);
  if ((t & 63) == 0) bits[b * 16 + (t >> 6)] = bal;
}

// ---- transpose-cast W [768][2304] f32 -> Wt [2304][768] bf16 ----
__global__ __launch_bounds__(256) void k_wt(const float* __restrict__ W, unsigned short* __restrict__ Wt) {
  __shared__ float tile[32][33];
  int r0 = blockIdx.x * 32;   // over 768
  int c0 = blockIdx.y * 32;   // over 2304
  int tx = threadIdx.x & 31, ty = threadIdx.x >> 5;
#pragma unroll
  for (int p = 0; p < 4; ++p)
    tile[ty + 8*p][tx] = W[(size_t)(r0 + ty + 8*p) * N3 + c0 + tx];
  __syncthreads();
#pragma unroll
  for (int p = 0; p < 4; ++p)
    Wt[(size_t)(c0 + ty + 8*p) * NHID + r0 + tx] = f2bf(tile[tx][ty + 8*p]);
}

// ---- QKV GEMM (m97-style): C[8192][2304] = A[8192][768] . Wt[2304][768]^T ----
__global__ __launch_bounds__(256) void k_qkv(const unsigned short* __restrict__ A,
                                             const unsigned short* __restrict__ Wt,
                                             const float* __restrict__ qb,
                                             const float* __restrict__ vb,
                                             unsigned short* __restrict__ out) {
  __shared__ __align__(16) unsigned short As[128 * 32];
  __shared__ __align__(16) unsigned short Bs[128 * 32];
  const int t = threadIdx.x;
  const int w = t >> 6, l = t & 63, l15 = l & 15, lhi = l >> 4;
  const int wr = w >> 1, wc = w & 1;
  const int rowbase = blockIdx.x * 128;
  const int colbase = blockIdx.y * 128;
  const int srow = l >> 2;           // 0..15 within a 16-row staging instr
  const int scol = (l & 3) * 8;      // shorts

  f32x4 acc[4][4] = {};

  for (int k0 = 0; k0 < NHID; k0 += 32) {
    __syncthreads();
#pragma unroll
    for (int i = 0; i < 2; ++i) {
      int rr = w * 32 + i * 16;
      gload_lds16(A  + (size_t)(rowbase + rr + srow) * NHID + k0 + scol, As + rr * 32);
      gload_lds16(Wt + (size_t)(colbase + rr + srow) * NHID + k0 + scol, Bs + rr * 32);
    }
    __syncthreads();
    short8 a[4], bfr[4];
#pragma unroll
    for (int mi = 0; mi < 4; ++mi)
      a[mi] = *(const short8*)(As + (wr * 64 + mi * 16 + l15) * 32 + lhi * 8);
#pragma unroll
    for (int ni = 0; ni < 4; ++ni)
      bfr[ni] = *(const short8*)(Bs + (wc * 64 + ni * 16 + l15) * 32 + lhi * 8);
#pragma unroll
    for (int mi = 0; mi < 4; ++mi)
#pragma unroll
      for (int ni = 0; ni < 4; ++ni)
        acc[mi][ni] = __builtin_amdgcn_mfma_f32_16x16x32_bf16(a[mi], bfr[ni], acc[mi][ni], 0, 0, 0);
  }

  const int seg = colbase / NHID;
#pragma unroll
  for (int ni = 0; ni < 4; ++ni) {
    int col = colbase + wc * 64 + ni * 16 + l15;
    int cc = col % NHID;
    float bias = (seg == 0) ? qb[cc] : (seg == 2) ? vb[cc] : 0.0f;
#pragma unroll
    for (int mi = 0; mi < 4; ++mi)
#pragma unroll
      for (int r = 0; r < 4; ++r) {
        int row = rowbase + wr * 64 + mi * 16 + lhi * 4 + r;
        float v = acc[mi][ni][r];
        if (seg == 0) v = (v + bias) * 0.125f;
        else if (seg == 2) v = v + bias;
        out[(size_t)row * N3 + col] = f2bf(v);
      }
  }
}

// ---- transpose V (cols 1536..2303 of qkv) -> Vt [96][64][1024] bf16 ----
__global__ __launch_bounds__(256) void k_vt(const unsigned short* __restrict__ qkvb,
                                            unsigned short* __restrict__ Vt) {
  __shared__ unsigned short tile[32][33];
  int s0 = blockIdx.x * 32;  // over 1024
  int d0 = blockIdx.y * 32;  // over 64
  int bh = blockIdx.z;       // 0..95
  int b = bh / NH;
  int hcol = (bh % NH) * ND;
  int tx = threadIdx.x & 31, ty = threadIdx.x >> 5;
#pragma unroll
  for (int p = 0; p < 4; ++p) {
    int s = s0 + ty + 8*p;
    tile[ty + 8*p][tx] = qkvb[(size_t)(b * NS + s) * N3 + 2 * NHID + hcol + d0 + tx];
  }
  __syncthreads();
#pragma unroll
  for (int p = 0; p < 4; ++p) {
    int d = d0 + ty + 8*p;
    Vt[((size_t)bh * ND + d) * NS + s0 + tx] = tile[tx][ty + 8*p];
  }
}

// ---- fused attention (R10 structure + contiguous probs row-writes) ----
// Block (qt,h,b): 16 q x 1024 keys, 4 waves, 8 chunks of 128 keys.
// Chunk loop unchanged from R10. Epilogue: packed P dumped to the freed Vs
// buffer [16][1024] (swizzled), then probs written as contiguous 1-KB-per-
// instruction row runs (4 instructions complete one 4-KB DRAM page).
__global__ __launch_bounds__(256, 2) void k_attn(const unsigned short* __restrict__ qkvb,
                                                 const unsigned short* __restrict__ Vt,
                                                 const float* __restrict__ relp,
                                                 const float* __restrict__ rel2,
                                                 const unsigned long long* __restrict__ mbits,
                                                 float* __restrict__ outp) {
  __shared__ __align__(16) char Ks[2][16384];           // [128 key][64 d] bf16, swz+rot
  __shared__ __align__(16) char Vs[2][16384];           // [64 d][128 key] bf16, swz+rot
  __shared__ __align__(16) char Rs[2][4096];            // [16 q][128 key] bf16 relsum, swz
  __shared__ __align__(16) unsigned short stg[4][16][40]; // per-wave P window
  __shared__ float rs_lds[4][16];
  __shared__ float inv_lds[16];

  const int qt = blockIdx.x, h = blockIdx.y, b = blockIdx.z;
  const int t = threadIdx.x, w = t >> 6, l = t & 63, l15 = l & 15, lhi = l >> 4;
  const int bh = b * NH + h;

  const int skk = t >> 1;            // K key-row 0..127
  const int skc = (t & 1) * 64;      // K byte-col base
  const int svd = t >> 2;            // V d-row 0..63
  const int svc = (t & 3) * 64;      // V byte-col base
  const int srr = t >> 4;            // rel q-row 0..15
  const int src = (t & 15) * 8;      // rel f32-col base
  const int kwz = (skk & 7) << 4, vwz = (svd & 7) << 4, rwz = (srr & 7) << 4;
  const int rotw = (skk >> 3) & 3;
  const int rotv = ((svd >> 3) & 1) + 2 * ((svc >> 7) & 1);

  const unsigned short* qrowp = qkvb + (size_t)(b * NS + qt * 16 + l15) * N3 + h * ND;
  short8 qa0 = *(const short8*)(qrowp + lhi * 8);
  short8 qa1 = *(const short8*)(qrowp + 32 + lhi * 8);

  unsigned long long mw[8];
#pragma unroll
  for (int c = 0; c < 8; ++c) mw[c] = mbits[b * 16 + c * 2 + (w >> 1)];

  const unsigned short* kgbase = qkvb + (size_t)(b * NS + skk) * N3 + NHID + h * ND + (skc >> 1);
  const unsigned short* vgbase = Vt + (size_t)(bh * ND + svd) * NS + (svc >> 1);
  const float* rgbase  = relp + ((size_t)(bh * NS + qt * 16 + srr)) * NS + src;
  const float* r2gbase = rel2 + ((size_t)(bh * NS + qt * 16 + srr)) * NS + src;

  short8 kr0, kr1, kr2, kr3, vr0, vr1, vr2, vr3;
  float4 ra0, ra1, rb0, rb1;

#define STAGE_LOAD(c) do {                                              \
    const unsigned short* kg = kgbase + (size_t)(c) * 128 * N3;         \
    kr0 = *(const short8*)(kg);      kr1 = *(const short8*)(kg + 8);    \
    kr2 = *(const short8*)(kg + 16); kr3 = *(const short8*)(kg + 24);   \
    const unsigned short* vg = vgbase + (c) * 128;                      \
    vr0 = *(const short8*)(vg);      vr1 = *(const short8*)(vg + 8);    \
    vr2 = *(const short8*)(vg + 16); vr3 = *(const short8*)(vg + 24);   \
    const float* rg = rgbase + (c) * 128;                               \
    ra0 = *(const float4*)(rg);  ra1 = *(const float4*)(rg + 4);        \
    const float* r2g = r2gbase + (c) * 128;                             \
    rb0 = *(const float4*)(r2g); rb1 = *(const float4*)(r2g + 4);       \
  } while (0)

#define STAGE_WRITE(buf) do {                                                     \
    char* KB = Ks[buf];                                                           \
    *(short8*)(KB + skk * 128 + ((skc + 16 * ((0 + rotw) & 3)) ^ kwz)) = kr0;     \
    *(short8*)(KB + skk * 128 + ((skc + 16 * ((1 + rotw) & 3)) ^ kwz)) = kr1;     \
    *(short8*)(KB + skk * 128 + ((skc + 16 * ((2 + rotw) & 3)) ^ kwz)) = kr2;     \
    *(short8*)(KB + skk * 128 + ((skc + 16 * ((3 + rotw) & 3)) ^ kwz)) = kr3;     \
    char* VB = Vs[buf];                                                           \
    *(short8*)(VB + svd * 256 + ((svc + 16 * ((0 + rotv) & 3)) ^ vwz)) = vr0;     \
    *(short8*)(VB + svd * 256 + ((svc + 16 * ((1 + rotv) & 3)) ^ vwz)) = vr1;     \
    *(short8*)(VB + svd * 256 + ((svc + 16 * ((2 + rotv) & 3)) ^ vwz)) = vr2;     \
    *(short8*)(VB + svd * 256 + ((svc + 16 * ((3 + rotv) & 3)) ^ vwz)) = vr3;     \
    char* RB = Rs[buf];                                                           \
    ushort4 u0, u1;                                                               \
    u0.x = f2bf(ra0.x + rb0.x); u0.y = f2bf(ra0.y + rb0.y);                       \
    u0.z = f2bf(ra0.z + rb0.z); u0.w = f2bf(ra0.w + rb0.w);                       \
    u1.x = f2bf(ra1.x + rb1.x); u1.y = f2bf(ra1.y + rb1.y);                       \
    u1.z = f2bf(ra1.z + rb1.z); u1.w = f2bf(ra1.w + rb1.w);                       \
    *(ushort4*)(RB + srr * 256 + ((src * 2 + 0) ^ rwz)) = u0;                     \
    *(ushort4*)(RB + srr * 256 + ((src * 2 + 8) ^ rwz)) = u1;                     \
  } while (0)

  unsigned int pkA[8][2], pkB[8][2];
  f32x4 cacc[4] = {};
  float rs = 0.f;

  STAGE_LOAD(0);
#pragma unroll
  for (int c = 0; c < 8; ++c) {
    const int buf = c & 1;
    STAGE_WRITE(buf);              // waits chunk c's loads (issued last iter)
    SBAR();
    if (c < 7) STAGE_LOAD(c + 1);  // in flight across the whole consume
    SBAR();
    __syncthreads();               // chunk c visible to all waves

    // ---- consume chunk c ----
    const char* KB = Ks[buf]; const char* VB = Vs[buf]; const char* RB = Rs[buf];
#pragma unroll
    for (int s = 0; s < 2; ++s) {
      int kkr = w * 32 + s * 16 + l15;
      int kx = (kkr & 7) << 4;
      int rotr = (kkr >> 3) & 3;
      short8 kf0 = *(const short8*)(KB + kkr * 128 + ((16 * ((lhi + rotr) & 3)) ^ kx));
      short8 kf1 = *(const short8*)(KB + kkr * 128 + ((64 + 16 * ((lhi + rotr) & 3)) ^ kx));
      f32x4 sc = {};
      sc = __builtin_amdgcn_mfma_f32_16x16x32_bf16(kf0, qa0, sc, 0, 0, 0);
      sc = __builtin_amdgcn_mfma_f32_16x16x32_bf16(kf1, qa1, sc, 0, 0, 0);
      ushort4 rsu = *(const ushort4*)(RB + l15 * 256 + ((w * 64 + s * 32 + lhi * 8) ^ ((l15 & 7) << 4)));
      int mb = (int)((mw[c] >> ((w & 1) * 32 + s * 16 + lhi * 4)) & 0xFull);
      float p0 = (mb & 1) ? 0.f : __expf(sc[0] + bf2f(rsu.x));
      float p1 = (mb & 2) ? 0.f : __expf(sc[1] + bf2f(rsu.y));
      float p2 = (mb & 4) ? 0.f : __expf(sc[2] + bf2f(rsu.z));
      float p3 = (mb & 8) ? 0.f : __expf(sc[3] + bf2f(rsu.w));
      rs += (p0 + p1) + (p2 + p3);
      ushort4 pw;
      pw.x = f2bf(p0); pw.y = f2bf(p1); pw.z = f2bf(p2); pw.w = f2bf(p3);
      pkA[c][s] = (unsigned int)pw.x | ((unsigned int)pw.y << 16);
      pkB[c][s] = (unsigned int)pw.z | ((unsigned int)pw.w << 16);
      *(ushort4*)(&stg[w][l15][s * 16 + lhi * 4]) = pw;
    }
    SBAR();                        // stage writes before pa read (wave in-order)
    short8 pa = *(const short8*)(&stg[w][l15][lhi * 8]);
#pragma unroll
    for (int n = 0; n < 4; ++n) {
      int dr = n * 16 + l15;
      int rotvr = ((dr >> 3) & 1) + 2 * ((w >> 1) & 1);
      short8 vf = *(const short8*)(VB + dr * 256 + ((w * 64 + 16 * ((lhi + rotvr) & 3)) ^ ((dr & 7) << 4)));
      cacc[n] = __builtin_amdgcn_mfma_f32_16x16x32_bf16(pa, vf, cacc[n], 0, 0, 0);
    }
  }

  // row sums -> inv  (this barrier also retires all PV reads of Ks/Vs)
  rs += __shfl_xor(rs, 16);
  rs += __shfl_xor(rs, 32);
  if (lhi == 0) rs_lds[w][l15] = rs;
  __syncthreads();
  if (t < 16)
    inv_lds[t] = 1.0f / (rs_lds[0][t] + rs_lds[1][t] + rs_lds[2][t] + rs_lds[3][t]);

  // dump packed P (bf16) into freed Vs as [16][1024] swizzled,
  // and ctx partials into freed Ks; one barrier covers both.
  {
    char* PB = (char*)Vs;
    int psw = (l15 & 7) << 4;
#pragma unroll
    for (int c = 0; c < 8; ++c)
#pragma unroll
      for (int s = 0; s < 2; ++s) {
        int colb = (c * 128 + w * 32 + s * 16 + lhi * 4) * 2;
        uint2 u; u.x = pkA[c][s]; u.y = pkB[c][s];
        *(uint2*)(PB + l15 * 2048 + (colb ^ psw)) = u;
      }
  }
  {
    float* cpart = (float*)Ks;
#pragma unroll
    for (int n = 0; n < 4; ++n)
#pragma unroll
      for (int r = 0; r < 4; ++r)
        cpart[w * 1024 + (lhi * 4 + r) * 64 + n * 16 + l15] = cacc[n][r];
  }
  __syncthreads();

  // probs out: contiguous 1-KB-per-instruction row runs (4 per 4-KB row)
  {
    float* probs = outp + (size_t)NB * NS * NHID;
    const char* PB = (const char*)Vs;
#pragma unroll
    for (int rr = 0; rr < 4; ++rr) {
      int row = w * 4 + rr;
      float inv = inv_lds[row];
      int sz = (row & 7) << 4;
      size_t base = ((size_t)bh * NS + qt * 16 + row) * NS;
#pragma unroll
      for (int i = 0; i < 4; ++i) {
        int cols = 4 * l + 256 * i;
        ushort4 pv = *(const ushort4*)(PB + row * 2048 + ((cols * 2) ^ sz));
        float4 o;
        o.x = bf2f(pv.x) * inv;
        o.y = bf2f(pv.y) * inv;
        o.z = bf2f(pv.z) * inv;
        o.w = bf2f(pv.w) * inv;
        *(float4*)(&probs[base + cols]) = o;
      }
    }
  }

  // ctx reduce + store
  {
    const float* cpart = (const float*)Ks;
#pragma unroll
    for (int i = 0; i < 4; ++i) {
      int idx = t + 256 * i;
      int q = idx >> 6, d = idx & 63;
      float s = cpart[idx] + cpart[1024 + idx] + cpart[2048 + idx] + cpart[3072 + idx];
      outp[(size_t)(b * NS + qt * 16 + q) * NHID + h * ND + d] = s * inv_lds[q];
    }
  }
#undef STAGE_LOAD
#undef STAGE_WRITE
}

extern "C" void kernel_launch(void* const* d_in, const int* in_sizes, int n_in,
                              void* d_out, int out_size, void* d_ws, size_t ws_size,
                              hipStream_t stream) {
  const float* hidden = (const float*)d_in[0];
  const int* mask = (const int*)d_in[1];
  const float* relp = (const float*)d_in[2];
  const float* rel2 = (const float*)d_in[3];
  const float* Wq = (const float*)d_in[4];
  const float* qb = (const float*)d_in[5];
  const float* vb = (const float*)d_in[6];
  float* out = (float*)d_out;

  const size_t OFF_AHS = 0;                       // 8192*768*2
  const size_t OFF_WT  = 12582912;                // 2304*768*2
  const size_t OFF_QKV = 16121856;                // 8192*2304*2
  const size_t OFF_VT  = 53870592;                // 96*64*1024*2
  const size_t OFF_MB  = 66453504;                // 8*16*8 = 1024
  if (ws_size < 66454528) return;

  char* ws = (char*)d_ws;
  unsigned short* Ahs  = (unsigned short*)(ws + OFF_AHS);
  unsigned short* Wt   = (unsigned short*)(ws + OFF_WT);
  unsigned short* qkvb = (unsigned short*)(ws + OFF_QKV);
  unsigned short* Vt   = (unsigned short*)(ws + OFF_VT);
  unsigned long long* mb = (unsigned long long*)(ws + OFF_MB);

  k_cast<<<dim3(6144), dim3(256), 0, stream>>>(hidden, Ahs, (NB * NS * NHID) / 4);
  k_mask<<<dim3(8), dim3(1024), 0, stream>>>(mask, mb);
  k_wt<<<dim3(24, 72), dim3(256), 0, stream>>>(Wq, Wt);
  k_qkv<<<dim3(64, 18), dim3(256), 0, stream>>>(Ahs, Wt, qb, vb, qkvb);
  k_vt<<<dim3(32, 2, 96), dim3(256), 0, stream>>>(qkvb, Vt);
  k_attn<<<dim3(64, 12, 8), dim3(256), 0, stream>>>(qkvb, Vt, relp, rel2, mb, out);
}

// Round 13
// 347.868 us; speedup vs baseline: 1.5649x; 1.0422x over previous
//
#include <hip/hip_runtime.h>
#include <hip/hip_bf16.h>

typedef __attribute__((ext_vector_type(8))) short short8;
typedef __attribute__((ext_vector_type(4))) float f32x4;

#define NB 8
#define NS 1024
#define NH 12
#define ND 64
#define NHID 768
#define N3 2304

#define SBAR() __builtin_amdgcn_sched_barrier(0)

__device__ __forceinline__ unsigned short f2bf(float f) {
  __hip_bfloat16 h = __float2bfloat16(f);
  return *reinterpret_cast<unsigned short*>(&h);
}
__device__ __forceinline__ float bf2f(unsigned short u) {
  __hip_bfloat16 h;
  *reinterpret_cast<unsigned short*>(&h) = u;
  return __bfloat162float(h);
}

__device__ __forceinline__ void gload_lds16(const unsigned short* g, unsigned short* l) {
  __builtin_amdgcn_global_load_lds(
      (const __attribute__((address_space(1))) unsigned int*)g,
      (__attribute__((address_space(3))) unsigned int*)l, 16, 0, 0);
}

// ---- cast hidden f32 -> bf16 ----
__global__ void k_cast(const float* __restrict__ in, unsigned short* __restrict__ out, int n4) {
  int i = blockIdx.x * blockDim.x + threadIdx.x;
  if (i >= n4) return;
  float4 v = ((const float4*)in)[i];
  ushort4 o;
  o.x = f2bf(v.x); o.y = f2bf(v.y); o.z = f2bf(v.z); o.w = f2bf(v.w);
  ((ushort4*)out)[i] = o;
}

// ---- pack mask [B][S] int -> bitmask [B][16] u64 ----
__global__ void k_mask(const int* __restrict__ mask, unsigned long long* __restrict__ bits) {
  int b = blockIdx.x, t = threadIdx.x;
  unsigned long long bal = __ballot(mask[b * NS + t] != 0);
  if ((t & 63) == 0) bits[b * 16 + (t >> 6)] = bal;
}

// ---- transpose-cast W [768][2304] f32 -> Wt [2304][768] bf16 ----
__global__ __launch_bounds__(256) void k_wt(const float* __restrict__ W, unsigned short* __restrict__ Wt) {
  __shared__ float tile[32][33];
  int r0 = blockIdx.x * 32;   // over 768
  int c0 = blockIdx.y * 32;   // over 2304
  int tx = threadIdx.x & 31, ty = threadIdx.x >> 5;
#pragma unroll
  for (int p = 0; p < 4; ++p)
    tile[ty + 8*p][tx] = W[(size_t)(r0 + ty + 8*p) * N3 + c0 + tx];
  __syncthreads();
#pragma unroll
  for (int p = 0; p < 4; ++p)
    Wt[(size_t)(c0 + ty + 8*p) * NHID + r0 + tx] = f2bf(tile[tx][ty + 8*p]);
}

// ---- QKV GEMM (m97-style): C[8192][2304] = A[8192][768] . Wt[2304][768]^T ----
__global__ __launch_bounds__(256) void k_qkv(const unsigned short* __restrict__ A,
                                             const unsigned short* __restrict__ Wt,
                                             const float* __restrict__ qb,
                                             const float* __restrict__ vb,
                                             unsigned short* __restrict__ out) {
  __shared__ __align__(16) unsigned short As[128 * 32];
  __shared__ __align__(16) unsigned short Bs[128 * 32];
  const int t = threadIdx.x;
  const int w = t >> 6, l = t & 63, l15 = l & 15, lhi = l >> 4;
  const int wr = w >> 1, wc = w & 1;
  const int rowbase = blockIdx.x * 128;
  const int colbase = blockIdx.y * 128;
  const int srow = l >> 2;           // 0..15 within a 16-row staging instr
  const int scol = (l & 3) * 8;      // shorts

  f32x4 acc[4][4] = {};

  for (int k0 = 0; k0 < NHID; k0 += 32) {
    __syncthreads();
#pragma unroll
    for (int i = 0; i < 2; ++i) {
      int rr = w * 32 + i * 16;
      gload_lds16(A  + (size_t)(rowbase + rr + srow) * NHID + k0 + scol, As + rr * 32);
      gload_lds16(Wt + (size_t)(colbase + rr + srow) * NHID + k0 + scol, Bs + rr * 32);
    }
    __syncthreads();
    short8 a[4], bfr[4];
#pragma unroll
    for (int mi = 0; mi < 4; ++mi)
      a[mi] = *(const short8*)(As + (wr * 64 + mi * 16 + l15) * 32 + lhi * 8);
#pragma unroll
    for (int ni = 0; ni < 4; ++ni)
      bfr[ni] = *(const short8*)(Bs + (wc * 64 + ni * 16 + l15) * 32 + lhi * 8);
#pragma unroll
    for (int mi = 0; mi < 4; ++mi)
#pragma unroll
      for (int ni = 0; ni < 4; ++ni)
        acc[mi][ni] = __builtin_amdgcn_mfma_f32_16x16x32_bf16(a[mi], bfr[ni], acc[mi][ni], 0, 0, 0);
  }

  const int seg = colbase / NHID;
#pragma unroll
  for (int ni = 0; ni < 4; ++ni) {
    int col = colbase + wc * 64 + ni * 16 + l15;
    int cc = col % NHID;
    float bias = (seg == 0) ? qb[cc] : (seg == 2) ? vb[cc] : 0.0f;
#pragma unroll
    for (int mi = 0; mi < 4; ++mi)
#pragma unroll
      for (int r = 0; r < 4; ++r) {
        int row = rowbase + wr * 64 + mi * 16 + lhi * 4 + r;
        float v = acc[mi][ni][r];
        if (seg == 0) v = (v + bias) * 0.125f;
        else if (seg == 2) v = v + bias;
        out[(size_t)row * N3 + col] = f2bf(v);
      }
  }
}

// ---- transpose V (cols 1536..2303 of qkv) -> Vt [96][64][1024] bf16 ----
__global__ __launch_bounds__(256) void k_vt(const unsigned short* __restrict__ qkvb,
                                            unsigned short* __restrict__ Vt) {
  __shared__ unsigned short tile[32][33];
  int s0 = blockIdx.x * 32;  // over 1024
  int d0 = blockIdx.y * 32;  // over 64
  int bh = blockIdx.z;       // 0..95
  int b = bh / NH;
  int hcol = (bh % NH) * ND;
  int tx = threadIdx.x & 31, ty = threadIdx.x >> 5;
#pragma unroll
  for (int p = 0; p < 4; ++p) {
    int s = s0 + ty + 8*p;
    tile[ty + 8*p][tx] = qkvb[(size_t)(b * NS + s) * N3 + 2 * NHID + hcol + d0 + tx];
  }
  __syncthreads();
#pragma unroll
  for (int p = 0; p < 4; ++p) {
    int d = d0 + ty + 8*p;
    Vt[((size_t)bh * ND + d) * NS + s0 + tx] = tile[tx][ty + 8*p];
  }
}

// ---- fused attention (R11 + 3-deep register prefetch for rel/rel2) ----
// Block (qt,h,b): 16 q x 1024 keys, 4 waves, 8 chunks of 128 keys.
// K/V: 1-chunk-ahead LDS staging (L2-served, short latency). rel/rel2:
// 3 register slots, loads issued 3 chunks ahead (~2 full iterations of
// HBM-latency cover), summed+bf16'd into double-buffered Rs at write time.
__global__ __launch_bounds__(256, 2) void k_attn(const unsigned short* __restrict__ qkvb,
                                                 const unsigned short* __restrict__ Vt,
                                                 const float* __restrict__ relp,
                                                 const float* __restrict__ rel2,
                                                 const unsigned long long* __restrict__ mbits,
                                                 float* __restrict__ outp) {
  __shared__ __align__(16) char Ks[2][16384];           // [128 key][64 d] bf16, swz+rot
  __shared__ __align__(16) char Vs[2][16384];           // [64 d][128 key] bf16, swz+rot
  __shared__ __align__(16) char Rs[2][4096];            // [16 q][128 key] bf16 relsum, swz
  __shared__ __align__(16) unsigned short stg[4][16][40]; // per-wave P window
  __shared__ float rs_lds[4][16];
  __shared__ float inv_lds[16];

  const int qt = blockIdx.x, h = blockIdx.y, b = blockIdx.z;
  const int t = threadIdx.x, w = t >> 6, l = t & 63, l15 = l & 15, lhi = l >> 4;
  const int bh = b * NH + h;

  const int skk = t >> 1;            // K key-row 0..127
  const int skc = (t & 1) * 64;      // K byte-col base
  const int svd = t >> 2;            // V d-row 0..63
  const int svc = (t & 3) * 64;      // V byte-col base
  const int srr = t >> 4;            // rel q-row 0..15
  const int src = (t & 15) * 8;      // rel f32-col base
  const int kwz = (skk & 7) << 4, vwz = (svd & 7) << 4, rwz = (srr & 7) << 4;
  const int rotw = (skk >> 3) & 3;
  const int rotv = ((svd >> 3) & 1) + 2 * ((svc >> 7) & 1);

  const unsigned short* qrowp = qkvb + (size_t)(b * NS + qt * 16 + l15) * N3 + h * ND;
  short8 qa0 = *(const short8*)(qrowp + lhi * 8);
  short8 qa1 = *(const short8*)(qrowp + 32 + lhi * 8);

  unsigned long long mw[8];
#pragma unroll
  for (int c = 0; c < 8; ++c) mw[c] = mbits[b * 16 + c * 2 + (w >> 1)];

  const unsigned short* kgbase = qkvb + (size_t)(b * NS + skk) * N3 + NHID + h * ND + (skc >> 1);
  const unsigned short* vgbase = Vt + (size_t)(bh * ND + svd) * NS + (svc >> 1);
  const float* rgbase  = relp + ((size_t)(bh * NS + qt * 16 + srr)) * NS + src;
  const float* r2gbase = rel2 + ((size_t)(bh * NS + qt * 16 + srr)) * NS + src;

  short8 kr0, kr1, kr2, kr3, vr0, vr1, vr2, vr3;
  float4 relA[3][2], rel2A[3][2];    // 3-deep rel prefetch slots (static idx)

#define KV_LOAD(c) do {                                                 \
    const unsigned short* kg = kgbase + (size_t)(c) * 128 * N3;         \
    kr0 = *(const short8*)(kg);      kr1 = *(const short8*)(kg + 8);    \
    kr2 = *(const short8*)(kg + 16); kr3 = *(const short8*)(kg + 24);   \
    const unsigned short* vg = vgbase + (c) * 128;                      \
    vr0 = *(const short8*)(vg);      vr1 = *(const short8*)(vg + 8);    \
    vr2 = *(const short8*)(vg + 16); vr3 = *(const short8*)(vg + 24);   \
  } while (0)

#define R_LOAD(c, sl) do {                                              \
    const float* rg = rgbase + (c) * 128;                               \
    relA[sl][0]  = *(const float4*)(rg);                                \
    relA[sl][1]  = *(const float4*)(rg + 4);                            \
    const float* r2g = r2gbase + (c) * 128;                             \
    rel2A[sl][0] = *(const float4*)(r2g);                               \
    rel2A[sl][1] = *(const float4*)(r2g + 4);                           \
  } while (0)

#define KV_WRITE(buf) do {                                                        \
    char* KB = Ks[buf];                                                           \
    *(short8*)(KB + skk * 128 + ((skc + 16 * ((0 + rotw) & 3)) ^ kwz)) = kr0;     \
    *(short8*)(KB + skk * 128 + ((skc + 16 * ((1 + rotw) & 3)) ^ kwz)) = kr1;     \
    *(short8*)(KB + skk * 128 + ((skc + 16 * ((2 + rotw) & 3)) ^ kwz)) = kr2;     \
    *(short8*)(KB + skk * 128 + ((skc + 16 * ((3 + rotw) & 3)) ^ kwz)) = kr3;     \
    char* VB = Vs[buf];                                                           \
    *(short8*)(VB + svd * 256 + ((svc + 16 * ((0 + rotv) & 3)) ^ vwz)) = vr0;     \
    *(short8*)(VB + svd * 256 + ((svc + 16 * ((1 + rotv) & 3)) ^ vwz)) = vr1;     \
    *(short8*)(VB + svd * 256 + ((svc + 16 * ((2 + rotv) & 3)) ^ vwz)) = vr2;     \
    *(short8*)(VB + svd * 256 + ((svc + 16 * ((3 + rotv) & 3)) ^ vwz)) = vr3;     \
  } while (0)

#define R_WRITE(buf, sl) do {                                                     \
    char* RB = Rs[buf];                                                           \
    ushort4 u0, u1;                                                               \
    u0.x = f2bf(relA[sl][0].x + rel2A[sl][0].x);                                  \
    u0.y = f2bf(relA[sl][0].y + rel2A[sl][0].y);                                  \
    u0.z = f2bf(relA[sl][0].z + rel2A[sl][0].z);                                  \
    u0.w = f2bf(relA[sl][0].w + rel2A[sl][0].w);                                  \
    u1.x = f2bf(relA[sl][1].x + rel2A[sl][1].x);                                  \
    u1.y = f2bf(relA[sl][1].y + rel2A[sl][1].y);                                  \
    u1.z = f2bf(relA[sl][1].z + rel2A[sl][1].z);                                  \
    u1.w = f2bf(relA[sl][1].w + rel2A[sl][1].w);                                  \
    *(ushort4*)(RB + srr * 256 + ((src * 2 + 0) ^ rwz)) = u0;                     \
    *(ushort4*)(RB + srr * 256 + ((src * 2 + 8) ^ rwz)) = u1;                     \
  } while (0)

  unsigned int pkA[8][2], pkB[8][2];
  f32x4 cacc[4] = {};
  float rs = 0.f;

  R_LOAD(0, 0); R_LOAD(1, 1); R_LOAD(2, 2);
  KV_LOAD(0);
#pragma unroll
  for (int c = 0; c < 8; ++c) {
    const int buf = c & 1;
    KV_WRITE(buf);                 // waits chunk c's K/V loads (1 iter old)
    R_WRITE(buf, c % 3);           // waits chunk c's rel loads (3 iters old)
    SBAR();
    if (c < 7) KV_LOAD(c + 1);     // L2-latency cover: 1 consume phase
    if (c < 5) R_LOAD(c + 3, c % 3); // HBM-latency cover: ~2 full iterations
    SBAR();
    __syncthreads();               // chunk c visible to all waves

    // ---- consume chunk c ----
    const char* KB = Ks[buf]; const char* VB = Vs[buf]; const char* RB = Rs[buf];
#pragma unroll
    for (int s = 0; s < 2; ++s) {
      int kkr = w * 32 + s * 16 + l15;
      int kx = (kkr & 7) << 4;
      int rotr = (kkr >> 3) & 3;
      short8 kf0 = *(const short8*)(KB + kkr * 128 + ((16 * ((lhi + rotr) & 3)) ^ kx));
      short8 kf1 = *(const short8*)(KB + kkr * 128 + ((64 + 16 * ((lhi + rotr) & 3)) ^ kx));
      f32x4 sc = {};
      sc = __builtin_amdgcn_mfma_f32_16x16x32_bf16(kf0, qa0, sc, 0, 0, 0);
      sc = __builtin_amdgcn_mfma_f32_16x16x32_bf16(kf1, qa1, sc, 0, 0, 0);
      ushort4 rsu = *(const ushort4*)(RB + l15 * 256 + ((w * 64 + s * 32 + lhi * 8) ^ ((l15 & 7) << 4)));
      int mb = (int)((mw[c] >> ((w & 1) * 32 + s * 16 + lhi * 4)) & 0xFull);
      float p0 = (mb & 1) ? 0.f : __expf(sc[0] + bf2f(rsu.x));
      float p1 = (mb & 2) ? 0.f : __expf(sc[1] + bf2f(rsu.y));
      float p2 = (mb & 4) ? 0.f : __expf(sc[2] + bf2f(rsu.z));
      float p3 = (mb & 8) ? 0.f : __expf(sc[3] + bf2f(rsu.w));
      rs += (p0 + p1) + (p2 + p3);
      ushort4 pw;
      pw.x = f2bf(p0); pw.y = f2bf(p1); pw.z = f2bf(p2); pw.w = f2bf(p3);
      pkA[c][s] = (unsigned int)pw.x | ((unsigned int)pw.y << 16);
      pkB[c][s] = (unsigned int)pw.z | ((unsigned int)pw.w << 16);
      *(ushort4*)(&stg[w][l15][s * 16 + lhi * 4]) = pw;
    }
    SBAR();                        // stage writes before pa read (wave in-order)
    short8 pa = *(const short8*)(&stg[w][l15][lhi * 8]);
#pragma unroll
    for (int n = 0; n < 4; ++n) {
      int dr = n * 16 + l15;
      int rotvr = ((dr >> 3) & 1) + 2 * ((w >> 1) & 1);
      short8 vf = *(const short8*)(VB + dr * 256 + ((w * 64 + 16 * ((lhi + rotvr) & 3)) ^ ((dr & 7) << 4)));
      cacc[n] = __builtin_amdgcn_mfma_f32_16x16x32_bf16(pa, vf, cacc[n], 0, 0, 0);
    }
  }

  // row sums -> inv  (this barrier also retires all PV reads of Ks/Vs)
  rs += __shfl_xor(rs, 16);
  rs += __shfl_xor(rs, 32);
  if (lhi == 0) rs_lds[w][l15] = rs;
  __syncthreads();
  if (t < 16)
    inv_lds[t] = 1.0f / (rs_lds[0][t] + rs_lds[1][t] + rs_lds[2][t] + rs_lds[3][t]);

  // dump packed P (bf16) into freed Vs as [16][1024] swizzled,
  // and ctx partials into freed Ks; one barrier covers both.
  {
    char* PB = (char*)Vs;
    int psw = (l15 & 7) << 4;
#pragma unroll
    for (int c = 0; c < 8; ++c)
#pragma unroll
      for (int s = 0; s < 2; ++s) {
        int colb = (c * 128 + w * 32 + s * 16 + lhi * 4) * 2;
        uint2 u; u.x = pkA[c][s]; u.y = pkB[c][s];
        *(uint2*)(PB + l15 * 2048 + (colb ^ psw)) = u;
      }
  }
  {
    float* cpart = (float*)Ks;
#pragma unroll
    for (int n = 0; n < 4; ++n)
#pragma unroll
      for (int r = 0; r < 4; ++r)
        cpart[w * 1024 + (lhi * 4 + r) * 64 + n * 16 + l15] = cacc[n][r];
  }
  __syncthreads();

  // probs out: contiguous 1-KB-per-instruction row runs (4 per 4-KB row)
  {
    float* probs = outp + (size_t)NB * NS * NHID;
    const char* PB = (const char*)Vs;
#pragma unroll
    for (int rr = 0; rr < 4; ++rr) {
      int row = w * 4 + rr;
      float inv = inv_lds[row];
      int sz = (row & 7) << 4;
      size_t base = ((size_t)bh * NS + qt * 16 + row) * NS;
#pragma unroll
      for (int i = 0; i < 4; ++i) {
        int cols = 4 * l + 256 * i;
        ushort4 pv = *(const ushort4*)(PB + row * 2048 + ((cols * 2) ^ sz));
        float4 o;
        o.x = bf2f(pv.x) * inv;
        o.y = bf2f(pv.y) * inv;
        o.z = bf2f(pv.z) * inv;
        o.w = bf2f(pv.w) * inv;
        *(float4*)(&probs[base + cols]) = o;
      }
    }
  }

  // ctx reduce + store
  {
    const float* cpart = (const float*)Ks;
#pragma unroll
    for (int i = 0; i < 4; ++i) {
      int idx = t + 256 * i;
      int q = idx >> 6, d = idx & 63;
      float s = cpart[idx] + cpart[1024 + idx] + cpart[2048 + idx] + cpart[3072 + idx];
      outp[(size_t)(b * NS + qt * 16 + q) * NHID + h * ND + d] = s * inv_lds[q];
    }
  }
#undef KV_LOAD
#undef R_LOAD
#undef KV_WRITE
#undef R_WRITE
}

extern "C" void kernel_launch(void* const* d_in, const int* in_sizes, int n_in,
                              void* d_out, int out_size, void* d_ws, size_t ws_size,
                              hipStream_t stream) {
  const float* hidden = (const float*)d_in[0];
  const int* mask = (const int*)d_in[1];
  const float* relp = (const float*)d_in[2];
  const float* rel2 = (const float*)d_in[3];
  const float* Wq = (const float*)d_in[4];
  const float* qb = (const float*)d_in[5];
  const float* vb = (const float*)d_in[6];
  float* out = (float*)d_out;

  const size_t OFF_AHS = 0;                       // 8192*768*2
  const size_t OFF_WT  = 12582912;                // 2304*768*2
  const size_t OFF_QKV = 16121856;                // 8192*2304*2
  const size_t OFF_VT  = 53870592;                // 96*64*1024*2
  const size_t OFF_MB  = 66453504;                // 8*16*8 = 1024
  if (ws_size < 66454528) return;

  char* ws = (char*)d_ws;
  unsigned short* Ahs  = (unsigned short*)(ws + OFF_AHS);
  unsigned short* Wt   = (unsigned short*)(ws + OFF_WT);
  unsigned short* qkvb = (unsigned short*)(ws + OFF_QKV);
  unsigned short* Vt   = (unsigned short*)(ws + OFF_VT);
  unsigned long long* mb = (unsigned long long*)(ws + OFF_MB);

  k_cast<<<dim3(6144), dim3(256), 0, stream>>>(hidden, Ahs, (NB * NS * NHID) / 4);
  k_mask<<<dim3(8), dim3(1024), 0, stream>>>(mask, mb);
  k_wt<<<dim3(24, 72), dim3(256), 0, stream>>>(Wq, Wt);
  k_qkv<<<dim3(64, 18), dim3(256), 0, stream>>>(Ahs, Wt, qb, vb, qkvb);
  k_vt<<<dim3(32, 2, 96), dim3(256), 0, stream>>>(qkvb, Vt);
  k_attn<<<dim3(64, 12, 8), dim3(256), 0, stream>>>(qkvb, Vt, relp, rel2, mb, out);
}